// Round 3
// baseline (107347.632 us; speedup 1.0000x reference)
//
#include <hip/hip_runtime.h>
#include <math.h>

#define TSTEPS  16384
#define NTAGS   1024
#define NSLOTS  32       // participating WGs, elected onto ONE XCD
#define TPB     256      // 4 waves/WG, 8 rows/wave -> 1024 rows total
#define NLAUNCH 2048     // shells; pigeonhole: some XCD sees >= 256 claimants
#define START_I 1022
#define STOP_I  1023
#define FAST_BUDGET 16   // fast sc0 sweeps before agent-scope fallback

// CRF forward, linear (exp) domain — R3: XCD-local ring, hang-proof.
//
// R2 post-mortem: no-fallback design; sc0-only stores park the fresh value
// as a dirty line in ONE L2, so any mis-binned reader (XCC_ID wrong, sc0
// semantics wrong) spins forever. R3 invariant: stores are agent-scope
// write-through (sc0 sc1 -> local L2 updated AND MALL updated), so
//   - fast path: same-XCD readers hit the updated L2 with sc0 loads (~200cy)
//   - fallback:  ANY reader can read fresh data from MALL (agent load)
// Every outcome is correct; only speed varies. Poll loops carry a 16-sweep
// budget before dropping to the fallback for that read.
//
//   p_{t+1} = e_t . (M p_t) / max(p_t),  S += log(max(p_t))
//   alpha   = S + log( sum_i p_T[i] * exp(trans[STOP,i]) )
//
// Validation embedded in data: stored value = sign(t)*(p+1), sign flips
// every ring wrap (depth-2 ring); poison/stale values never validate.
// Main loop is 8x unrolled: ring parity (t&1) and sign ((t>>1)&1) are
// static per unroll index, and decoded emissions are prefetched 8 steps
// at a time (32B contiguous per wave) so the poll's vmcnt(0) never drains
// a fresh HBM load more than once per 8 steps.

typedef float f32x4 __attribute__((ext_vector_type(4)));

__device__ __forceinline__ float min16(const float v[16]) {
    float a = fminf(v[0],  v[1]),  b = fminf(v[2],  v[3]);
    float c = fminf(v[4],  v[5]),  d = fminf(v[6],  v[7]);
    float e = fminf(v[8],  v[9]),  f = fminf(v[10], v[11]);
    float g = fminf(v[12], v[13]), h = fminf(v[14], v[15]);
    a = fminf(a, b); c = fminf(c, d); e = fminf(e, f); g = fminf(g, h);
    return fminf(fminf(a, c), fminf(e, g));
}
__device__ __forceinline__ float max16(const float v[16]) {
    float a = fmaxf(v[0],  v[1]),  b = fmaxf(v[2],  v[3]);
    float c = fmaxf(v[4],  v[5]),  d = fmaxf(v[6],  v[7]);
    float e = fmaxf(v[8],  v[9]),  f = fmaxf(v[10], v[11]);
    float g = fmaxf(v[12], v[13]), h = fmaxf(v[14], v[15]);
    a = fmaxf(a, b); c = fmaxf(c, d); e = fmaxf(e, f); g = fmaxf(g, h);
    return fmaxf(fmaxf(a, c), fmaxf(e, g));
}

// Acquire a validated 16-float snapshot of this lane's columns.
// fast_src = ring slot + 4*lane (16B aligned; groups at +256 floats).
template <bool POS>
__device__ __forceinline__ void poll_read(const float* fast_src, float v[16]) {
    int budget = FAST_BUDGET;
    for (;;) {
        f32x4 q0, q1, q2, q3;
        asm volatile(
            "global_load_dwordx4 %0, %4, off sc0\n\t"
            "global_load_dwordx4 %1, %4, off offset:1024 sc0\n\t"
            "global_load_dwordx4 %2, %4, off offset:2048 sc0\n\t"
            "global_load_dwordx4 %3, %4, off offset:3072 sc0\n\t"
            "s_waitcnt vmcnt(0)"
            : "=&v"(q0), "=&v"(q1), "=&v"(q2), "=&v"(q3)
            : "v"(fast_src)
            : "memory");
        v[0]  = q0[0]; v[1]  = q0[1]; v[2]  = q0[2]; v[3]  = q0[3];
        v[4]  = q1[0]; v[5]  = q1[1]; v[6]  = q1[2]; v[7]  = q1[3];
        v[8]  = q2[0]; v[9]  = q2[1]; v[10] = q2[2]; v[11] = q2[3];
        v[12] = q3[0]; v[13] = q3[1]; v[14] = q3[2]; v[15] = q3[3];
        if (POS) { if (min16(v) >=  1.0f) return; }
        else     { if (max16(v) <= -1.0f) return; }
        if (--budget <= 0) break;
    }
    // Agent-scope fallback: stores are write-through to MALL, so this is
    // guaranteed to make progress no matter where this wave landed.
    const unsigned long long* src = (const unsigned long long*)fast_src;
    for (;;) {
        unsigned long long q[8];
        #pragma unroll
        for (int k = 0; k < 4; ++k) {
            q[2*k]   = __hip_atomic_load(src + 128*k,     __ATOMIC_RELAXED,
                                         __HIP_MEMORY_SCOPE_AGENT);
            q[2*k+1] = __hip_atomic_load(src + 128*k + 1, __ATOMIC_RELAXED,
                                         __HIP_MEMORY_SCOPE_AGENT);
        }
        #pragma unroll
        for (int k = 0; k < 4; ++k) {
            v[4*k]   = __uint_as_float((unsigned)q[2*k]);
            v[4*k+1] = __uint_as_float((unsigned)(q[2*k] >> 32));
            v[4*k+2] = __uint_as_float((unsigned)q[2*k+1]);
            v[4*k+3] = __uint_as_float((unsigned)(q[2*k+1] >> 32));
        }
        if (POS) { if (min16(v) >=  1.0f) return; }
        else     { if (max16(v) <= -1.0f) return; }
    }
}

// Sum each of 8 accumulators over all 64 lanes; lane ends with the sum for
// accumulator index (lane>>3). 17 shfl + 7 selects.
__device__ __forceinline__ float reduce8(float a[8], int lane) {
    #pragma unroll
    for (int i = 0; i < 8; ++i) a[i] += __shfl_xor(a[i], 32, 64);
    float g0 = (lane & 32) ? a[4] : a[0];
    float g1 = (lane & 32) ? a[5] : a[1];
    float g2 = (lane & 32) ? a[6] : a[2];
    float g3 = (lane & 32) ? a[7] : a[3];
    g0 += __shfl_xor(g0, 16, 64); g1 += __shfl_xor(g1, 16, 64);
    g2 += __shfl_xor(g2, 16, 64); g3 += __shfl_xor(g3, 16, 64);
    float h0 = (lane & 16) ? g2 : g0;
    float h1 = (lane & 16) ? g3 : g1;
    h0 += __shfl_xor(h0, 8, 64); h1 += __shfl_xor(h1, 8, 64);
    float b = (lane & 8) ? h1 : h0;
    b += __shfl_xor(b, 4, 64);
    b += __shfl_xor(b, 2, 64);
    b += __shfl_xor(b, 1, 64);
    return b;
}

__global__ __launch_bounds__(TPB, 1)
void crf_forward_kernel(const float* __restrict__ decoded,
                        const float* __restrict__ trans,
                        float* __restrict__ out,
                        float* __restrict__ ws)
{
    float* ring   = ws;                       // 2 * 1024 floats
    int*   cnt    = (int*)(ws + 2 * NTAGS);   // per-XCD claim counters [8]
    int*   winner = cnt + 8;                  // elected XCD id (-1 = none)

    // ---- election: first XCD to accumulate NSLOTS claimants wins.
    // If XCC_ID is garbage the election still terminates (pigeonhole) and
    // the scattered "winners" run correctly via the fallback path.
    __shared__ int s_slot;
    if (threadIdx.x == 0) {
        unsigned xcc = (unsigned)__builtin_amdgcn_s_getreg((31 << 11) | 20) & 7u;
        int slot = -1;
        int c = __hip_atomic_fetch_add(&cnt[xcc], 1, __ATOMIC_RELAXED,
                                       __HIP_MEMORY_SCOPE_AGENT);
        if (c < NSLOTS) {
            if (c == NSLOTS - 1) atomicCAS(winner, -1, (int)xcc);
            int w;
            do {
                __builtin_amdgcn_s_sleep(2);
                w = __hip_atomic_load(winner, __ATOMIC_RELAXED,
                                      __HIP_MEMORY_SCOPE_AGENT);
            } while (w < 0);
            if (w == (int)xcc) slot = c;
        }
        s_slot = slot;
    }
    __syncthreads();
    const int slot = s_slot;        // uniform per WG
    if (slot < 0) return;           // shell WG: exit, free the CU

    const int tid  = threadIdx.x;
    const int lane = tid & 63;
    const int wid  = tid >> 6;              // 0..3
    const int r0   = slot * 32 + wid * 8;   // this wave's 8 output rows

    // ---- init: M fragments; v[4k+j] <-> column c = 256k + 4*lane + j ----
    float M[8][16];
    float sm[8];
    #pragma unroll
    for (int r = 0; r < 8; ++r) {
        sm[r] = 0.0f;
        const float* tr = trans + (size_t)(r0 + r) * NTAGS;
        #pragma unroll
        for (int k = 0; k < 4; ++k)
            #pragma unroll
            for (int j = 0; j < 4; ++j) {
                const float m = __expf(tr[256 * k + 4 * lane + j]);
                M[r][4 * k + j] = m;
                sm[r] += m;
            }
    }
    const float msum = reduce8(sm, lane);    // lane: sum(M[r0+(lane>>3),:])

    const bool storer = ((lane & 7) == 0);   // lanes 0,8,..,56 -> 8 rows
    const int  myrow  = r0 + (lane >> 3);

    double s2 = 0.0;                 // sum log2(max), uniform per wave
    float dbuf[8] = {}, dn[8] = {};  // emissions, batched 8 timesteps
    if (storer) {
        #pragma unroll
        for (int i = 0; i < 8; ++i)
            dbuf[i] = decoded[(size_t)i * NTAGS + myrow];
    }

    for (int tb = 0; tb < TSTEPS; tb += 8) {
        #pragma unroll
        for (int u = 0; u < 8; ++u) {
            // static per u: ring parity = u&1, sign sg = ((u>>1)&1)?-:+
            const bool POS = (((u >> 1) & 1) == 0);
            const float sg = POS ? 1.0f : -1.0f;

            float v[16];
            if (tb == 0 && u == 0) {
                #pragma unroll
                for (int k = 0; k < 4; ++k)
                    #pragma unroll
                    for (int j = 0; j < 4; ++j)
                        v[4*k+j] = (256*k + 4*lane + j == START_I) ? 2.0f : 1.0f;
            } else {
                const float* fsrc = ring + (size_t)(u & 1) * NTAGS + 4 * lane;
                if (POS) poll_read<true >(fsrc, v);
                else     poll_read<false>(fsrc, v);
            }

            // batched emission prefetch for the NEXT block (once per 8 steps;
            // 32B contiguous across the 8 storer lanes)
            if (u == 0 && storer && tb + 8 < TSTEPS) {
                #pragma unroll
                for (int i = 0; i < 8; ++i)
                    dn[i] = decoded[(size_t)(tb + 8 + i) * NTAGS + myrow];
            }

            const float e    = __expf(dbuf[u]);          // off critical path
            const float Eraw = POS ? max16(v) : min16(v);

            // dot products on raw v (sign/offset folded into msum)
            float a[8];
            #pragma unroll
            for (int r = 0; r < 8; ++r) a[r] = 0.0f;
            #pragma unroll
            for (int r = 0; r < 8; ++r)
                #pragma unroll
                for (int j = 0; j < 16; ++j)
                    a[r] = fmaf(M[r][j], v[j], a[r]);

            // global max of pv across the wave (identical in every wave)
            float ml = fmaf(sg, Eraw, -1.0f);
            ml = fmaxf(ml, __shfl_xor(ml, 32, 64));
            ml = fmaxf(ml, __shfl_xor(ml, 16, 64));
            ml = fmaxf(ml, __shfl_xor(ml,  8, 64));
            ml = fmaxf(ml, __shfl_xor(ml,  4, 64));
            ml = fmaxf(ml, __shfl_xor(ml,  2, 64));
            ml = fmaxf(ml, __shfl_xor(ml,  1, 64));

            const float b = reduce8(a, lane);   // row (lane>>3) dot product

            s2 += (double)__log2f(ml);          // off critical path

            if (storer) {
                const float s    = fmaf(sg, b, -msum);       // sum M . pv
                const float outv = e * s * __builtin_amdgcn_rcpf(ml);
                // static: store parity (u+1)&1, sign = (((u+1)>>1)&1)?-:+
                const float sgn  = (((u + 1) >> 1) & 1) ? -1.0f : 1.0f;
                const float sv   = fmaf(sgn, outv, sgn);     // sgn*(outv+1)
                // agent-scope write-through: updates local L2 (fast readers)
                // AND MALL (sound fallback)
                __hip_atomic_store(ring + (size_t)((u + 1) & 1) * NTAGS + myrow,
                                   sv, __ATOMIC_RELAXED,
                                   __HIP_MEMORY_SCOPE_AGENT);
            }
        }
        #pragma unroll
        for (int i = 0; i < 8; ++i) dbuf[i] = dn[i];
    }

    // ---- epilogue: slot 0 / wave 0 folds in trans[STOP,:] ----
    if (slot == 0 && wid == 0) {
        // p_T is in slot (TSTEPS&1)=0 with sign +1 ((TSTEPS>>1)&1 = 0)
        float v[16];
        poll_read<true>(ring + 4 * lane, v);
        float term = 0.0f;
        const float* tr = trans + (size_t)STOP_I * NTAGS;
        #pragma unroll
        for (int k = 0; k < 4; ++k)
            #pragma unroll
            for (int j = 0; j < 4; ++j)
                term = fmaf(__expf(tr[256 * k + 4 * lane + j]),
                            v[4 * k + j] - 1.0f, term);
        term += __shfl_xor(term, 32, 64);
        term += __shfl_xor(term, 16, 64);
        term += __shfl_xor(term,  8, 64);
        term += __shfl_xor(term,  4, 64);
        term += __shfl_xor(term,  2, 64);
        term += __shfl_xor(term,  1, 64);
        if (lane == 0)
            out[0] = (float)(0.6931471805599453 * (s2 + log2((double)term)));
    }
}

extern "C" void kernel_launch(void* const* d_in, const int* in_sizes, int n_in,
                              void* d_out, int out_size, void* d_ws, size_t ws_size,
                              hipStream_t stream) {
    const float* decoded = (const float*)d_in[0];   // [16384, 1024] f32
    const float* trans   = (const float*)d_in[1];   // [1024, 1024]  f32
    float* out  = (float*)d_out;
    float* ring = (float*)d_ws;                     // 2*1024 f32 + cnt[8] + winner

    // ring poison (validation-invalid regardless of harness poisoning),
    // claim counters = 0, winner = -1 (0xFFFFFFFF)
    hipMemsetAsync(ring, 0xAA, 2 * NTAGS * sizeof(float), stream);
    hipMemsetAsync((char*)ring + 2 * NTAGS * sizeof(float), 0x00, 32, stream);
    hipMemsetAsync((char*)ring + 2 * NTAGS * sizeof(float) + 32, 0xFF, 4, stream);

    hipLaunchKernelGGL(crf_forward_kernel, dim3(NLAUNCH), dim3(TPB), 0, stream,
                       decoded, trans, out, ring);
}

// Round 5
// 57337.518 us; speedup vs baseline: 1.8722x; 1.8722x over previous
//
#include <hip/hip_runtime.h>
#include <math.h>

#define TSTEPS  16384
#define NTAGS   1024
#define NSLOTS  32       // participating WGs, elected onto ONE XCD
#define TPB     256      // 4 compute waves, 8 rows/wave
#define NLAUNCH 2048     // shells; pigeonhole: some XCD sees >= 256 claimants
#define START_I 1022
#define STOP_I  1023
#define SLOW_EVERY    4  // 1 slow sweep per 4 fast sweeps while stuck
#define TROUBLE_ITERS 64 // iterations before flagging trouble / republishing

// CRF forward, linear domain — R5: dirty-L2 fast ring + EXACT-TAGGED slow ring.
//
// R4 post-mortem: publisher's signature-skip was unsound (tp-2 vs tp+2
// indistinguishable) and slow_read could block while its only feeders were
// themselves blocked. R5 removes the publisher entirely:
//  - fast ring: plain stores (dirty line in winner-XCD L2) + sc0 polls.
//  - slow ring: u64 entries (exact_step_tag<<32 | raw_value). Tag match is
//    exact — no period-4 sign aliasing, 8B atomics prevent tearing.
//  - liveness: a stuck wave republishes its last TWO produced values (held
//    in registers) every 64 spin iters — unconditional, needs no partner.
//    If the minimal stuck reader waits on labels t, every wave's frontier
//    is >= t, so every stuck wave's republish pair includes t -> progress.
//  - a global trouble flag (set by any stuck wave, checked every 32 steps)
//    turns on dualstore everywhere for steady slow-ring feeding.
// Every outcome is correct; fast-path health only affects speed.
//
//   p_{t+1} = e_t . (M p_t) / max(p_t),  S += log(max(p_t))
//   alpha   = S + log( sum_i p_T[i] * exp(trans[STOP,i]) )
// Fast-ring encoding: value = sign(t)*(p+1), sign period 4; poison/stale
// never validate (and label t is stable while anyone still polls it).

typedef float f32x4 __attribute__((ext_vector_type(4)));
typedef unsigned long long u64_t;

static __device__ __forceinline__ float min16(const float v[16]) {
    float a = fminf(v[0],  v[1]),  b = fminf(v[2],  v[3]);
    float c = fminf(v[4],  v[5]),  d = fminf(v[6],  v[7]);
    float e = fminf(v[8],  v[9]),  f = fminf(v[10], v[11]);
    float g = fminf(v[12], v[13]), h = fminf(v[14], v[15]);
    a = fminf(a, b); c = fminf(c, d); e = fminf(e, f); g = fminf(g, h);
    return fminf(fminf(a, c), fminf(e, g));
}
static __device__ __forceinline__ float max16(const float v[16]) {
    float a = fmaxf(v[0],  v[1]),  b = fmaxf(v[2],  v[3]);
    float c = fmaxf(v[4],  v[5]),  d = fmaxf(v[6],  v[7]);
    float e = fmaxf(v[8],  v[9]),  f = fmaxf(v[10], v[11]);
    float g = fmaxf(v[12], v[13]), h = fmaxf(v[14], v[15]);
    a = fmaxf(a, b); c = fmaxf(c, d); e = fmaxf(e, f); g = fmaxf(g, h);
    return fmaxf(fmaxf(a, c), fmaxf(e, g));
}

// One fast sweep: 4x dwordx4 sc0 loads (bypass L1, served by this XCD's L2).
static __device__ __forceinline__ void fast_sweep(const float* src, float w[16]) {
    f32x4 q0, q1, q2, q3;
    asm volatile(
        "global_load_dwordx4 %0, %4, off sc0\n\t"
        "global_load_dwordx4 %1, %4, off offset:1024 sc0\n\t"
        "global_load_dwordx4 %2, %4, off offset:2048 sc0\n\t"
        "global_load_dwordx4 %3, %4, off offset:3072 sc0\n\t"
        "s_waitcnt vmcnt(0)"
        : "=&v"(q0), "=&v"(q1), "=&v"(q2), "=&v"(q3)
        : "v"(src) : "memory");
    w[0]  = q0[0]; w[1]  = q0[1]; w[2]  = q0[2]; w[3]  = q0[3];
    w[4]  = q1[0]; w[5]  = q1[1]; w[6]  = q1[2]; w[7]  = q1[3];
    w[8]  = q2[0]; w[9]  = q2[1]; w[10] = q2[2]; w[11] = q2[3];
    w[12] = q3[0]; w[13] = q3[1]; w[14] = q3[2]; w[15] = q3[3];
}

static __device__ __forceinline__ u64_t packts(int tag, float raw) {
    return ((u64_t)(unsigned)tag << 32) | (u64_t)__float_as_uint(raw);
}

// Acquire validated inputs for step t (labels t). Fast sc0 sweeps with
// periodic exact-tag slow sweeps; stuck waves flag trouble and republish
// their register-held frontier (labels t, t-1) — unconditional liveness.
template <bool POS>
static __device__ __forceinline__ void acquire(
        int t, int lane, const float* fsrc, const u64_t* ssrc,
        u64_t* slowring, int myrow, bool storer, float r1, float r0,
        int* trouble, bool& troubleset, float v[16])
{
    bool have = false;
    int iters = 0;
    #pragma unroll 1
    for (;;) {
        float w[16];
        fast_sweep(fsrc, w);
        if (!have) {
            const float ext = POS ? min16(w) : max16(w);
            const bool  ok  = POS ? (ext >= 1.0f) : (ext <= -1.0f);
            if (ok) {
                #pragma unroll
                for (int j = 0; j < 16; ++j) v[j] = w[j];
                have = true;
            }
        }
        if (__all(have)) return;
        ++iters;
        if ((iters & (SLOW_EVERY - 1)) == 0 && !have) {
            bool good = true;
            float tmp[16];
            #pragma unroll
            for (int k = 0; k < 4; ++k)
                #pragma unroll
                for (int j = 0; j < 4; ++j) {
                    const u64_t q = __hip_atomic_load(ssrc + 256 * k + j,
                        __ATOMIC_RELAXED, __HIP_MEMORY_SCOPE_AGENT);
                    if ((unsigned)(q >> 32) != (unsigned)t) good = false;
                    const float raw = __uint_as_float((unsigned)q);
                    tmp[4*k+j] = POS ? (raw + 1.0f) : -(raw + 1.0f);
                }
            if (good) {
                #pragma unroll
                for (int j = 0; j < 16; ++j) v[j] = tmp[j];
                have = true;
            }
            if (__all(have)) return;
        }
        if ((iters & (TROUBLE_ITERS - 1)) == 0) {
            if (!troubleset) {
                if (lane == 0)
                    __hip_atomic_store(trouble, 1, __ATOMIC_RELAXED,
                                       __HIP_MEMORY_SCOPE_AGENT);
                troubleset = true;
            }
            if (storer) {   // republish frontier: labels t and t-1
                __hip_atomic_store(slowring + (size_t)(t & 1) * NTAGS + myrow,
                    packts(t, r1), __ATOMIC_RELAXED, __HIP_MEMORY_SCOPE_AGENT);
                __hip_atomic_store(slowring + (size_t)((t-1) & 1) * NTAGS + myrow,
                    packts(t-1, r0), __ATOMIC_RELAXED, __HIP_MEMORY_SCOPE_AGENT);
            }
        }
    }
}

// Sum 8 accumulators over 64 lanes; lane ends with sum for index (lane>>3).
static __device__ __forceinline__ float reduce8(float a[8], int lane) {
    #pragma unroll
    for (int i = 0; i < 8; ++i) a[i] += __shfl_xor(a[i], 32, 64);
    float g0 = (lane & 32) ? a[4] : a[0];
    float g1 = (lane & 32) ? a[5] : a[1];
    float g2 = (lane & 32) ? a[6] : a[2];
    float g3 = (lane & 32) ? a[7] : a[3];
    g0 += __shfl_xor(g0, 16, 64); g1 += __shfl_xor(g1, 16, 64);
    g2 += __shfl_xor(g2, 16, 64); g3 += __shfl_xor(g3, 16, 64);
    float h0 = (lane & 16) ? g2 : g0;
    float h1 = (lane & 16) ? g3 : g1;
    h0 += __shfl_xor(h0, 8, 64); h1 += __shfl_xor(h1, 8, 64);
    float b = (lane & 8) ? h1 : h0;
    b += __shfl_xor(b, 4, 64);
    b += __shfl_xor(b, 2, 64);
    b += __shfl_xor(b, 1, 64);
    return b;
}

__global__ __launch_bounds__(TPB, 1)
void crf_forward_kernel(const float* __restrict__ decoded,
                        const float* __restrict__ trans,
                        float* __restrict__ out,
                        float* __restrict__ ws)
{
    float* fastring = ws;                       // [2][1024] f32, plain-store
    u64_t* slowring = (u64_t*)(ws + 2 * NTAGS); // [2][1024] u64, agent-scope
    int*   ibase    = (int*)(ws + 6 * NTAGS);   // cnt[8], ready, trouble, winner
    int*   cnt      = ibase;
    int*   ready    = ibase + 8;
    int*   trouble  = ibase + 9;
    int*   winner   = ibase + 10;

    __shared__ int s_slot;
    const int tid = threadIdx.x;
    if (tid == 0) {
        unsigned xcc = (unsigned)__builtin_amdgcn_s_getreg((31u << 11) | 20) & 7u;
        int slotv = -1;
        int c = __hip_atomic_fetch_add(&cnt[xcc], 1, __ATOMIC_RELAXED,
                                       __HIP_MEMORY_SCOPE_AGENT);
        if (c < NSLOTS) {
            if (c == NSLOTS - 1) atomicCAS(winner, -1, (int)xcc);
            int w;
            do {
                __builtin_amdgcn_s_sleep(2);
                w = __hip_atomic_load(winner, __ATOMIC_RELAXED,
                                      __HIP_MEMORY_SCOPE_AGENT);
            } while (w < 0);
            if (w == (int)xcc) slotv = c;
        }
        s_slot = slotv;
    }
    __syncthreads();
    const int slot = s_slot;
    if (slot < 0) return;            // shell WG: exit, free the CU

    const int  lane   = tid & 63;
    const int  wid    = tid >> 6;                    // 0..3
    const bool storer = ((lane & 7) == 0);
    const int  myrow  = slot * 32 + wid * 8 + (lane >> 3);

    // Poison own fast rows with PLAIN stores (establishes dirty lines in OUR
    // L2 so polls never see stale MALL/prior-launch data), then agent barrier.
    if (storer) {
        const float poison = __uint_as_float(0xAAAAAAAAu);
        asm volatile("global_store_dword %0, %1, off"
                     :: "v"(fastring + myrow), "v"(poison) : "memory");
        asm volatile("global_store_dword %0, %1, off"
                     :: "v"(fastring + NTAGS + myrow), "v"(poison) : "memory");
    }
    asm volatile("s_waitcnt vmcnt(0)" ::: "memory");
    __syncthreads();
    if (tid == 0) {
        __hip_atomic_fetch_add(ready, 1, __ATOMIC_RELAXED,
                               __HIP_MEMORY_SCOPE_AGENT);
        while (__hip_atomic_load(ready, __ATOMIC_RELAXED,
                                 __HIP_MEMORY_SCOPE_AGENT) < NSLOTS)
            __builtin_amdgcn_s_sleep(1);
    }
    __syncthreads();

    // ---- M fragments; v[4k+j] <-> col c = 256k + 4*lane + j ----
    const int r0row = slot * 32 + wid * 8;
    float M[8][16];
    float sm[8];
    #pragma unroll
    for (int r = 0; r < 8; ++r) {
        sm[r] = 0.0f;
        const float* tr = trans + (size_t)(r0row + r) * NTAGS;
        #pragma unroll
        for (int k = 0; k < 4; ++k)
            #pragma unroll
            for (int j = 0; j < 4; ++j) {
                const float m = __expf(tr[256 * k + 4 * lane + j]);
                M[r][4 * k + j] = m;
                sm[r] += m;
            }
    }
    const float msum = reduce8(sm, lane);

    double s2 = 0.0;
    float dbuf[8] = {}, dn[8] = {};
    if (storer) {
        #pragma unroll
        for (int i = 0; i < 8; ++i)
            dbuf[i] = decoded[(size_t)i * NTAGS + myrow];
    }

    // frontier registers (raw p values): r1 = latest label, r0 = previous
    float r1 = (myrow == START_I) ? 1.0f : 0.0f;   // label 0 (init)
    float r0 = r1;
    bool dualstore = false, troubleset = false;

    for (int tb = 0; tb < TSTEPS; tb += 8) {
        #pragma unroll
        for (int u = 0; u < 8; ++u) {
            const int   t   = tb + u;
            const bool  POS = (((u >> 1) & 1) == 0);
            const float sg  = POS ? 1.0f : -1.0f;

            float v[16];
            if (tb == 0 && u == 0) {
                #pragma unroll
                for (int k = 0; k < 4; ++k)
                    #pragma unroll
                    for (int j = 0; j < 4; ++j)
                        v[4*k+j] = (256*k + 4*lane + j == START_I) ? 2.0f : 1.0f;
            } else {
                const float* fsrc = fastring + (size_t)(u & 1) * NTAGS + 4 * lane;
                const u64_t* ssrc = slowring + (size_t)(u & 1) * NTAGS + 4 * lane;
                if (POS) acquire<true >(t, lane, fsrc, ssrc, slowring, myrow,
                                        storer, r1, r0, trouble, troubleset, v);
                else     acquire<false>(t, lane, fsrc, ssrc, slowring, myrow,
                                        storer, r1, r0, trouble, troubleset, v);
            }

            if (u == 0 && storer && tb + 8 < TSTEPS) {
                #pragma unroll
                for (int i = 0; i < 8; ++i)
                    dn[i] = decoded[(size_t)(tb + 8 + i) * NTAGS + myrow];
            }

            const float e    = __expf(dbuf[u]);
            const float Eraw = POS ? max16(v) : min16(v);

            float a[8];
            #pragma unroll
            for (int r = 0; r < 8; ++r) a[r] = 0.0f;
            #pragma unroll
            for (int r = 0; r < 8; ++r)
                #pragma unroll
                for (int j = 0; j < 16; ++j)
                    a[r] = fmaf(M[r][j], v[j], a[r]);

            float ml = fmaf(sg, Eraw, -1.0f);
            ml = fmaxf(ml, __shfl_xor(ml, 32, 64));
            ml = fmaxf(ml, __shfl_xor(ml, 16, 64));
            ml = fmaxf(ml, __shfl_xor(ml,  8, 64));
            ml = fmaxf(ml, __shfl_xor(ml,  4, 64));
            ml = fmaxf(ml, __shfl_xor(ml,  2, 64));
            ml = fmaxf(ml, __shfl_xor(ml,  1, 64));

            const float b = reduce8(a, lane);

            s2 += (double)__log2f(ml);

            if (storer) {
                const float s    = fmaf(sg, b, -msum);
                const float outv = e * s * __builtin_amdgcn_rcpf(ml);
                const float sgn  = (((u + 1) >> 1) & 1) ? -1.0f : 1.0f;
                const float sv   = fmaf(sgn, outv, sgn);     // sgn*(outv+1)
                float* fdst = fastring + (size_t)((u + 1) & 1) * NTAGS + myrow;
                asm volatile("global_store_dword %0, %1, off"
                             :: "v"(fdst), "v"(sv) : "memory");
                if (dualstore)
                    __hip_atomic_store(slowring + (size_t)((u+1) & 1) * NTAGS
                        + myrow, packts(t + 1, outv),
                        __ATOMIC_RELAXED, __HIP_MEMORY_SCOPE_AGENT);
                r0 = r1; r1 = outv;
            }

            if (!dualstore && ((t & 31) == 31)) {
                const int fl = __hip_atomic_load(trouble, __ATOMIC_RELAXED,
                                                 __HIP_MEMORY_SCOPE_AGENT);
                if (fl) {
                    dualstore = true;
                    if (storer) {   // publish current frontier immediately
                        __hip_atomic_store(slowring + (size_t)((t+1) & 1) * NTAGS
                            + myrow, packts(t + 1, r1),
                            __ATOMIC_RELAXED, __HIP_MEMORY_SCOPE_AGENT);
                        __hip_atomic_store(slowring + (size_t)(t & 1) * NTAGS
                            + myrow, packts(t, r0),
                            __ATOMIC_RELAXED, __HIP_MEMORY_SCOPE_AGENT);
                    }
                }
            }
        }
        #pragma unroll
        for (int i = 0; i < 8; ++i) dbuf[i] = dn[i];
    }

    // Final publish: make the last two labels MALL-visible unconditionally
    // (covers stragglers and the epilogue's slow fallback).
    if (storer) {
        __hip_atomic_store(slowring + (size_t)(TSTEPS & 1) * NTAGS + myrow,
            packts(TSTEPS, r1), __ATOMIC_RELAXED, __HIP_MEMORY_SCOPE_AGENT);
        __hip_atomic_store(slowring + (size_t)((TSTEPS-1) & 1) * NTAGS + myrow,
            packts(TSTEPS - 1, r0), __ATOMIC_RELAXED, __HIP_MEMORY_SCOPE_AGENT);
    }

    // ---- epilogue: slot 0 / wave 0 folds in trans[STOP,:] ----
    if (slot == 0 && wid == 0) {
        float v[16];   // labels TSTEPS: parity 0, sign +
        acquire<true>(TSTEPS, lane, fastring + 4 * lane, slowring + 4 * lane,
                      slowring, myrow, storer, r1, r0, trouble, troubleset, v);
        float term = 0.0f;
        const float* tr = trans + (size_t)STOP_I * NTAGS;
        #pragma unroll
        for (int k = 0; k < 4; ++k)
            #pragma unroll
            for (int j = 0; j < 4; ++j)
                term = fmaf(__expf(tr[256 * k + 4 * lane + j]),
                            v[4 * k + j] - 1.0f, term);
        term += __shfl_xor(term, 32, 64);
        term += __shfl_xor(term, 16, 64);
        term += __shfl_xor(term,  8, 64);
        term += __shfl_xor(term,  4, 64);
        term += __shfl_xor(term,  2, 64);
        term += __shfl_xor(term,  1, 64);
        if (lane == 0)
            out[0] = (float)(0.6931471805599453 * (s2 + log2((double)term)));
    }
}

extern "C" void kernel_launch(void* const* d_in, const int* in_sizes, int n_in,
                              void* d_out, int out_size, void* d_ws, size_t ws_size,
                              hipStream_t stream) {
    const float* decoded = (const float*)d_in[0];   // [16384, 1024] f32
    const float* trans   = (const float*)d_in[1];   // [1024, 1024]  f32
    float* out = (float*)d_out;
    float* ws  = (float*)d_ws;
    // layout: fast f32[2][1024] | slow u64[2][1024] | cnt[8],ready,trouble,winner

    // poison both rings (slow-ring tags 0xAAAAAAAA never match a real label)
    hipMemsetAsync(ws, 0xAA, 6 * NTAGS * sizeof(float), stream);
    // cnt[8] + ready + trouble = 0 ; winner = -1
    hipMemsetAsync((char*)ws + 6 * NTAGS * sizeof(float), 0x00, 40, stream);
    hipMemsetAsync((char*)ws + 6 * NTAGS * sizeof(float) + 40, 0xFF, 4, stream);

    hipLaunchKernelGGL(crf_forward_kernel, dim3(NLAUNCH), dim3(TPB), 0, stream,
                       decoded, trans, out, ws);
}